// Round 5
// baseline (27886.688 us; speedup 1.0000x reference)
//
#include <hip/hip_runtime.h>
#include <hip/hip_cooperative_groups.h>

namespace cg = cooperative_groups;

#define Bb 256
#define Tt 512
#define Dd 512
#define Hh 512
#define KTOT 1024
#define FOURH 2048

typedef __attribute__((ext_vector_type(8))) short bf16x8;
typedef __attribute__((ext_vector_type(4))) float f32x4;

__device__ __forceinline__ unsigned short f2bf(float f) {
    union { float f; unsigned u; } x; x.f = f;
    unsigned u = x.u;
    unsigned r = u + 0x7FFFu + ((u >> 16) & 1u);
    return (unsigned short)(r >> 16);
}
__device__ __forceinline__ float bf2f(unsigned short s) {
    union { unsigned u; float f; } x; x.u = ((unsigned)s) << 16;
    return x.f;
}

// Transpose + split W = [Wx; Wh] (K=1024 rows, N=2048 cols) into
// WT_hi/WT_lo layout [N=2048][K=1024] bf16 (k-contiguous per output column).
__global__ void prep_w(const float* __restrict__ Wx, const float* __restrict__ Wh,
                       unsigned short* __restrict__ WT_hi, unsigned short* __restrict__ WT_lo) {
    __shared__ float tile[32][33];
    int n0 = (blockIdx.x & 63) * 32;
    int k0 = (blockIdx.x >> 6) * 32;
    int tx = threadIdx.x & 31;
    int ty = threadIdx.x >> 5;
    for (int q = 0; q < 4; ++q) {
        int k = k0 + ty + q * 8;
        int n = n0 + tx;
        float v = (k < Dd) ? Wx[(size_t)k * FOURH + n] : Wh[(size_t)(k - Dd) * FOURH + n];
        tile[ty + q * 8][tx] = v;
    }
    __syncthreads();
    for (int q = 0; q < 4; ++q) {
        int nl = ty + q * 8;
        int kl = tx;
        float v = tile[kl][nl];
        unsigned short hi = f2bf(v);
        unsigned short lo = f2bf(v - bf2f(hi));
        size_t o = (size_t)(n0 + nl) * KTOT + (size_t)(k0 + kl);
        WT_hi[o] = hi;
        WT_lo[o] = lo;
    }
}

__global__ void init_state(float* __restrict__ c_st,
                           unsigned short* __restrict__ h_bufs) {
    int i = blockIdx.x * blockDim.x + threadIdx.x;
    if (i < Bb * Hh) {
        c_st[i] = 0.f;
        for (int q = 0; q < 4; ++q)
            h_bufs[(size_t)q * Bb * Hh + i] = 0;
    }
}

// ---------------- Persistent cooperative kernel: all 512 steps, 1 launch ----
// Grid: 256 WGs x 512 threads (1 WG/CU). WG tile: 32 rows x 16 h-cols x 4 gates.
// 8 waves: gate = w8&3, khalf = w8>>2 (K-half split). mi=0/1 row-subtiles.
// h double-buffered across steps; ONE grid.sync() per step orders
// writes(h,t) before reads(h,t) at t+1 (CG sync = device-scope fences).
// c held in a register per thread (each thread owns one (row,col) forever).
__global__ __launch_bounds__(512) void lstm_persist(
    const float* __restrict__ X, const int* __restrict__ lengths,
    const unsigned short* __restrict__ WT_hi, const unsigned short* __restrict__ WT_lo,
    const float* __restrict__ bias,
    unsigned short* __restrict__ h_base,
    float* __restrict__ out)
{
    cg::grid_group grid = cg::this_grid();
    __shared__ float zbuf[8][32][17];

    const int bx = blockIdx.x;            // 0..255
    const int xcd = bx & 7;
    const int i = bx >> 3;                // 0..31
    const int m0 = (i & 7) * 32;          // 8 row-tiles of 32
    const int col_group = xcd * 4 + (i >> 3);  // 0..31
    const int hc0 = col_group * 16;
    const int tid = threadIdx.x;
    const int w8 = tid >> 6;
    const int lane = tid & 63;
    const int gate = w8 & 3;
    const int khalf = w8 >> 2;

    const size_t HB = (size_t)Bb * Hh;
    unsigned short* h_hi0 = h_base;
    unsigned short* h_lo0 = h_base + HB;
    unsigned short* h_hi1 = h_base + 2 * HB;
    unsigned short* h_lo1 = h_base + 3 * HB;

    const int colk = gate * 512 + hc0 + (lane & 15);
    const size_t bbase = (size_t)colk * KTOT + (size_t)khalf * 512;
    const int klo = (lane >> 4) * 8;      // 0,8,16,24
    const int rowA = m0 + (lane & 15);    // mi=0 row; mi=1: +16

    // epilogue ownership: 1 element per thread
    const int er = tid >> 4;              // 0..31
    const int ej = tid & 15;              // 0..15
    const int row_g = m0 + er;
    const int col_g = hc0 + ej;
    const size_t oidx_mem = (size_t)row_g * Hh + col_g;
    int oT = lengths[row_g] - 1; if (oT < 0) oT = 0;
    const float b0 = bias[col_g], b1 = bias[512 + col_g],
                b2 = bias[1024 + col_g], b3 = bias[1536 + col_g];
    float creg = 0.f;

    const float* xr0 = &X[(size_t)rowA * Tt * Dd];
    const float* xr1 = &X[(size_t)(rowA + 16) * Tt * Dd];
    const size_t hoffA0 = (size_t)rowA * Hh;
    const size_t hoffA1 = (size_t)(rowA + 16) * Hh;
    const unsigned short* bhp = &WT_hi[bbase];
    const unsigned short* blp = &WT_lo[bbase];

    for (int t = 0; t < Tt; ++t) {
        const unsigned short* hrh = (t & 1) ? h_hi1 : h_hi0;
        const unsigned short* hrl = (t & 1) ? h_lo1 : h_lo0;
        unsigned short* hwh = (t & 1) ? h_hi0 : h_hi1;
        unsigned short* hwl = (t & 1) ? h_lo0 : h_lo1;

        f32x4 ahh0 = (f32x4){0,0,0,0}, ahl0 = (f32x4){0,0,0,0}, alh0 = (f32x4){0,0,0,0};
        f32x4 ahh1 = (f32x4){0,0,0,0}, ahl1 = (f32x4){0,0,0,0}, alh1 = (f32x4){0,0,0,0};

        if (khalf == 0) {
            const float* x0 = xr0 + (size_t)t * Dd;
            const float* x1 = xr1 + (size_t)t * Dd;
#pragma unroll
            for (int ks = 0; ks < 16; ++ks) {
                const int kk = ks * 32 + klo;
                bf16x8 ah0, al0, ah1, al1;
                {
                    const float4 v0 = *(const float4*)&x0[kk];
                    const float4 v1 = *(const float4*)&x0[kk + 4];
                    float vv[8] = {v0.x, v0.y, v0.z, v0.w, v1.x, v1.y, v1.z, v1.w};
#pragma unroll
                    for (int e = 0; e < 8; ++e) {
                        unsigned short hi = f2bf(vv[e]);
                        ah0[e] = (short)hi;
                        al0[e] = (short)f2bf(vv[e] - bf2f(hi));
                    }
                }
                {
                    const float4 v0 = *(const float4*)&x1[kk];
                    const float4 v1 = *(const float4*)&x1[kk + 4];
                    float vv[8] = {v0.x, v0.y, v0.z, v0.w, v1.x, v1.y, v1.z, v1.w};
#pragma unroll
                    for (int e = 0; e < 8; ++e) {
                        unsigned short hi = f2bf(vv[e]);
                        ah1[e] = (short)hi;
                        al1[e] = (short)f2bf(vv[e] - bf2f(hi));
                    }
                }
                const bf16x8 bh = *(const bf16x8*)&bhp[kk];
                const bf16x8 bl = *(const bf16x8*)&blp[kk];
                ahh0 = __builtin_amdgcn_mfma_f32_16x16x32_bf16(ah0, bh, ahh0, 0, 0, 0);
                ahl0 = __builtin_amdgcn_mfma_f32_16x16x32_bf16(ah0, bl, ahl0, 0, 0, 0);
                alh0 = __builtin_amdgcn_mfma_f32_16x16x32_bf16(al0, bh, alh0, 0, 0, 0);
                ahh1 = __builtin_amdgcn_mfma_f32_16x16x32_bf16(ah1, bh, ahh1, 0, 0, 0);
                ahl1 = __builtin_amdgcn_mfma_f32_16x16x32_bf16(ah1, bl, ahl1, 0, 0, 0);
                alh1 = __builtin_amdgcn_mfma_f32_16x16x32_bf16(al1, bh, alh1, 0, 0, 0);
            }
        } else {
#pragma unroll
            for (int ks = 0; ks < 16; ++ks) {
                const int kk = ks * 32 + klo;
                const bf16x8 ah0 = *(const bf16x8*)&hrh[hoffA0 + kk];
                const bf16x8 al0 = *(const bf16x8*)&hrl[hoffA0 + kk];
                const bf16x8 ah1 = *(const bf16x8*)&hrh[hoffA1 + kk];
                const bf16x8 al1 = *(const bf16x8*)&hrl[hoffA1 + kk];
                const bf16x8 bh = *(const bf16x8*)&bhp[kk];
                const bf16x8 bl = *(const bf16x8*)&blp[kk];
                ahh0 = __builtin_amdgcn_mfma_f32_16x16x32_bf16(ah0, bh, ahh0, 0, 0, 0);
                ahl0 = __builtin_amdgcn_mfma_f32_16x16x32_bf16(ah0, bl, ahl0, 0, 0, 0);
                alh0 = __builtin_amdgcn_mfma_f32_16x16x32_bf16(al0, bh, alh0, 0, 0, 0);
                ahh1 = __builtin_amdgcn_mfma_f32_16x16x32_bf16(ah1, bh, ahh1, 0, 0, 0);
                ahl1 = __builtin_amdgcn_mfma_f32_16x16x32_bf16(ah1, bl, ahl1, 0, 0, 0);
                alh1 = __builtin_amdgcn_mfma_f32_16x16x32_bf16(al1, bh, alh1, 0, 0, 0);
            }
        }

        const f32x4 z0 = ahh0 + ahl0 + alh0;
        const f32x4 z1 = ahh1 + ahl1 + alh1;
        // C/D layout: col = lane&15, row = (lane>>4)*4 + r
#pragma unroll
        for (int r = 0; r < 4; ++r) {
            zbuf[w8][(lane >> 4) * 4 + r][lane & 15] = z0[r];
            zbuf[w8][16 + (lane >> 4) * 4 + r][lane & 15] = z1[r];
        }
        __syncthreads();

        // epilogue: 1 elem per thread
        float zi = zbuf[0][er][ej] + zbuf[4][er][ej] + b0;
        float zf = zbuf[1][er][ej] + zbuf[5][er][ej] + b1;
        float zg = zbuf[2][er][ej] + zbuf[6][er][ej] + b2;
        float zo = zbuf[3][er][ej] + zbuf[7][er][ej] + b3;
        float ig = 1.f / (1.f + expf(-zi));
        float fg = 1.f / (1.f + expf(-zf));
        float gg = tanhf(zg);
        float og = 1.f / (1.f + expf(-zo));
        float cn = fg * creg + ig * gg;
        creg = cn;
        float hn = og * tanhf(cn);
        unsigned short hh = f2bf(hn);
        hwh[oidx_mem] = hh;
        hwl[oidx_mem] = f2bf(hn - bf2f(hh));
        if (t == oT) out[oidx_mem] = hn;

        grid.sync();
    }
}

// ---------------- Fallback: per-step kernel (round-4 proven path) ----------
__global__ __launch_bounds__(512) void lstm_step4(
    const float* __restrict__ X, const int* __restrict__ lengths,
    const unsigned short* __restrict__ WT_hi, const unsigned short* __restrict__ WT_lo,
    const float* __restrict__ bias,
    float* __restrict__ c_st,
    const unsigned short* __restrict__ h_r_hi, const unsigned short* __restrict__ h_r_lo,
    unsigned short* __restrict__ h_w_hi, unsigned short* __restrict__ h_w_lo,
    float* __restrict__ out, int t)
{
    __shared__ float zbuf[8][16][17];

    const int bx = blockIdx.x;
    const int xcd = bx & 7;
    const int rem = bx >> 3;
    const int m0 = (rem & 15) * 16;
    const int col_group = xcd * 4 + (rem >> 4);
    const int hc0 = col_group * 16;
    const int tid = threadIdx.x;
    const int w8 = tid >> 6;
    const int lane = tid & 63;
    const int gate = w8 & 3;
    const int khalf = w8 >> 2;

    f32x4 ahh = (f32x4){0,0,0,0}, ahl = (f32x4){0,0,0,0}, alh = (f32x4){0,0,0,0};

    const int colk = gate * 512 + hc0 + (lane & 15);
    const size_t bbase = (size_t)colk * KTOT;
    const int klo = (lane >> 4) * 8;
    const int row = m0 + (lane & 15);

    if (khalf == 0) {
        const float* xrow = &X[((size_t)row * Tt + t) * Dd];
        const unsigned short* bhp = &WT_hi[bbase];
        const unsigned short* blp = &WT_lo[bbase];
#pragma unroll
        for (int ks = 0; ks < 16; ++ks) {
            const int kk = ks * 32 + klo;
            const float4 v0 = *(const float4*)&xrow[kk];
            const float4 v1 = *(const float4*)&xrow[kk + 4];
            float vv[8] = {v0.x, v0.y, v0.z, v0.w, v1.x, v1.y, v1.z, v1.w};
            bf16x8 ah, al;
#pragma unroll
            for (int e = 0; e < 8; ++e) {
                unsigned short hi = f2bf(vv[e]);
                ah[e] = (short)hi;
                al[e] = (short)f2bf(vv[e] - bf2f(hi));
            }
            const bf16x8 bh = *(const bf16x8*)&bhp[kk];
            const bf16x8 bl = *(const bf16x8*)&blp[kk];
            ahh = __builtin_amdgcn_mfma_f32_16x16x32_bf16(ah, bh, ahh, 0, 0, 0);
            ahl = __builtin_amdgcn_mfma_f32_16x16x32_bf16(ah, bl, ahl, 0, 0, 0);
            alh = __builtin_amdgcn_mfma_f32_16x16x32_bf16(al, bh, alh, 0, 0, 0);
        }
    } else {
        const unsigned short* hrh = &h_r_hi[(size_t)row * Hh];
        const unsigned short* hrl = &h_r_lo[(size_t)row * Hh];
        const unsigned short* bhp = &WT_hi[bbase + 512];
        const unsigned short* blp = &WT_lo[bbase + 512];
#pragma unroll
        for (int ks = 0; ks < 16; ++ks) {
            const int kk = ks * 32 + klo;
            const bf16x8 ah = *(const bf16x8*)&hrh[kk];
            const bf16x8 al = *(const bf16x8*)&hrl[kk];
            const bf16x8 bh = *(const bf16x8*)&bhp[kk];
            const bf16x8 bl = *(const bf16x8*)&blp[kk];
            ahh = __builtin_amdgcn_mfma_f32_16x16x32_bf16(ah, bh, ahh, 0, 0, 0);
            ahl = __builtin_amdgcn_mfma_f32_16x16x32_bf16(ah, bl, ahl, 0, 0, 0);
            alh = __builtin_amdgcn_mfma_f32_16x16x32_bf16(al, bh, alh, 0, 0, 0);
        }
    }

    const f32x4 z = ahh + ahl + alh;
#pragma unroll
    for (int r = 0; r < 4; ++r)
        zbuf[w8][(lane >> 4) * 4 + r][lane & 15] = z[r];
    __syncthreads();

    if (tid < 256) {
        const int r = tid >> 4;
        const int j = tid & 15;
        const int row_g = m0 + r;
        const int col_g = hc0 + j;
        float zi = zbuf[0][r][j] + zbuf[4][r][j] + bias[col_g];
        float zf = zbuf[1][r][j] + zbuf[5][r][j] + bias[512 + col_g];
        float zg = zbuf[2][r][j] + zbuf[6][r][j] + bias[1024 + col_g];
        float zo = zbuf[3][r][j] + zbuf[7][r][j] + bias[1536 + col_g];
        float ig = 1.f / (1.f + expf(-zi));
        float fg = 1.f / (1.f + expf(-zf));
        float gg = tanhf(zg);
        float og = 1.f / (1.f + expf(-zo));
        const size_t idx = (size_t)row_g * Hh + col_g;
        float cn = fg * c_st[idx] + ig * gg;
        float hn = og * tanhf(cn);
        c_st[idx] = cn;
        unsigned short hh = f2bf(hn);
        h_w_hi[idx] = hh;
        h_w_lo[idx] = f2bf(hn - bf2f(hh));
        int len = lengths[row_g];
        int oidx = len - 1; if (oidx < 0) oidx = 0;
        if (t == oidx) out[idx] = hn;
    }
}

extern "C" void kernel_launch(void* const* d_in, const int* in_sizes, int n_in,
                              void* d_out, int out_size, void* d_ws, size_t ws_size,
                              hipStream_t stream) {
    const float* X = (const float*)d_in[0];
    const int* lengths = (const int*)d_in[1];
    const float* Wx = (const float*)d_in[2];
    const float* Wh = (const float*)d_in[3];
    const float* bias = (const float*)d_in[4];
    float* out = (float*)d_out;

    char* ws = (char*)d_ws;
    unsigned short* WT_hi = (unsigned short*)ws;                               // 4 MB
    unsigned short* WT_lo = (unsigned short*)(ws + (4u << 20));                // 4 MB
    float* c_st = (float*)(ws + (8u << 20));                                   // 512 KB
    unsigned short* h_base = (unsigned short*)(ws + (8u << 20) + (512u << 10));
    const size_t HB = (size_t)Bb * Hh;
    unsigned short* h_hi0 = h_base;
    unsigned short* h_lo0 = h_base + HB;
    unsigned short* h_hi1 = h_base + 2 * HB;
    unsigned short* h_lo1 = h_base + 3 * HB;

    hipLaunchKernelGGL(prep_w, dim3(2048), dim3(256), 0, stream, Wx, Wh, WT_hi, WT_lo);
    hipLaunchKernelGGL(init_state, dim3(512), dim3(256), 0, stream, c_st, h_base);

    void* args[] = { (void*)&X, (void*)&lengths, (void*)&WT_hi, (void*)&WT_lo,
                     (void*)&bias, (void*)&h_base, (void*)&out };
    hipError_t err = hipLaunchCooperativeKernel((const void*)lstm_persist,
                                                dim3(256), dim3(512), args, 0, stream);
    if (err != hipSuccess) {
        // Fallback: proven per-step path.
        for (int t = 0; t < Tt; ++t) {
            const bool even = (t & 1) == 0;
            hipLaunchKernelGGL(lstm_step4, dim3(512), dim3(512), 0, stream,
                               X, lengths, WT_hi, WT_lo, bias, c_st,
                               even ? h_hi0 : h_hi1, even ? h_lo0 : h_lo1,
                               even ? h_hi1 : h_hi0, even ? h_lo1 : h_lo0,
                               out, t);
        }
    }
}